// Round 14
// baseline (313.724 us; speedup 1.0000x reference)
//
#include <hip/hip_runtime.h>
#include <stdint.h>
#include <stddef.h>

typedef __attribute__((ext_vector_type(8))) short bf16x8;
typedef __attribute__((ext_vector_type(4))) float f32x4;

#define NROWS 400000
#define KC 128
#define DIMS 64
#define NTILES (NROWS / 16)

__device__ __forceinline__ short f2bf(float f) {
    union { float f; uint32_t u; } v; v.f = f;
    uint32_t u = v.u;
    uint32_t r = (u + 0x7FFFu + ((u >> 16) & 1u)) >> 16;  // RNE, finite inputs
    return (short)r;
}

__device__ __forceinline__ float frcp(float x) { return __builtin_amdgcn_rcpf(x); }

// Stage -2*centers bf16 A-fragments into LDS + center norms into cnLDS. (R8)
__device__ __forceinline__ void stage_centers_T(
        const float* __restrict__ centers, bf16x8 (*blds)[2][64],
        float* cnLDS, int wid, int lane, int m, int g)
{
    #pragma unroll
    for (int cb = 0; cb < 8; ++cb) {
        float cacc = 0.f;
        bf16x8 bfr[2];
        #pragma unroll
        for (int h = 0; h < 2; ++h) {
            const float* src = centers + (size_t)(cb * 16 + m) * DIMS + h * 32 + g * 8;
            f32x4 c0 = *(const f32x4*)src;
            f32x4 c1 = *(const f32x4*)(src + 4);
            bf16x8 b;
            #pragma unroll
            for (int j = 0; j < 4; ++j) {
                float f0 = c0[j], f1 = c1[j];
                cacc += f0 * f0 + f1 * f1;
                b[j]     = f2bf(-2.0f * f0);
                b[j + 4] = f2bf(-2.0f * f1);
            }
            bfr[h] = b;
        }
        cacc += __shfl_xor(cacc, 16);
        cacc += __shfl_xor(cacc, 32);
        if (wid == 0) {
            blds[cb][0][lane] = bfr[0];
            blds[cb][1][lane] = bfr[1];
            if (g == 0) cnLDS[cb * 16 + m] = cacc;
        }
    }
    __syncthreads();
}

// K1: colsum of q (R8 main loop, untouched) + fused last-block reduce -> invS/lS.
__global__ __launch_bounds__(256) void k1_colsum(
        const float* __restrict__ embeds, const float* __restrict__ centers,
        float* __restrict__ colsum_part, float* __restrict__ invS,
        float* __restrict__ lS, int* __restrict__ counter, int nblocks)
{
    __shared__ bf16x8 blds[8][2][64];
    __shared__ float cnLDS[128];
    __shared__ float cl[4 * 128];
    __shared__ float red[2][128];
    __shared__ int isLast;
    const int tid = threadIdx.x, wid = tid >> 6, lane = tid & 63;
    const int m = lane & 15, g = lane >> 4;

    stage_centers_T(centers, blds, cnLDS, wid, lane, m, g);

    f32x4 cnr[8];
    #pragma unroll
    for (int cb = 0; cb < 8; ++cb) cnr[cb] = *(const f32x4*)&cnLDS[cb * 16 + g * 4];

    float csum[8][4];
    #pragma unroll
    for (int cb = 0; cb < 8; ++cb)
        #pragma unroll
        for (int r = 0; r < 4; ++r) csum[cb][r] = 0.f;

    const int gwid = blockIdx.x * 4 + wid;
    const int nw = nblocks * 4;

    int t = gwid;
    f32x4 n0, n1, n2, n3;
    if (t < NTILES) {
        const float* src = embeds + (size_t)(t * 16 + m) * DIMS + g * 8;
        n0 = *(const f32x4*)src;       n1 = *(const f32x4*)(src + 4);
        n2 = *(const f32x4*)(src + 32); n3 = *(const f32x4*)(src + 36);
    }
    for (; t < NTILES; t += nw) {
        f32x4 c0 = n0, c1 = n1, c2 = n2, c3 = n3;
        int tn = t + nw;
        if (tn < NTILES) {
            const float* src = embeds + (size_t)(tn * 16 + m) * DIMS + g * 8;
            n0 = *(const f32x4*)src;       n1 = *(const f32x4*)(src + 4);
            n2 = *(const f32x4*)(src + 32); n3 = *(const f32x4*)(src + 36);
        }
        bf16x8 a0, a1;
        float en = 0.f;
        #pragma unroll
        for (int j = 0; j < 4; ++j) {
            float f0 = c0[j], f1 = c1[j], f2 = c2[j], f3 = c3[j];
            en += f0 * f0 + f1 * f1 + f2 * f2 + f3 * f3;
            a0[j] = f2bf(f0); a0[j + 4] = f2bf(f1);
            a1[j] = f2bf(f2); a1[j + 4] = f2bf(f3);
        }
        en += __shfl_xor(en, 16);
        en += __shfl_xor(en, 32);

        f32x4 acc[8];
        #pragma unroll
        for (int cb = 0; cb < 8; ++cb) {
            f32x4 a = {en, en, en, en};
            a = __builtin_amdgcn_mfma_f32_16x16x32_bf16(blds[cb][0][lane], a0, a, 0, 0, 0);
            a = __builtin_amdgcn_mfma_f32_16x16x32_bf16(blds[cb][1][lane], a1, a, 0, 0, 0);
            acc[cb] = a;
        }

        float rsp = 0.f;
        #pragma unroll
        for (int cb = 0; cb < 8; ++cb)
            #pragma unroll
            for (int r = 0; r < 4; ++r) {
                float sq = fmaxf(acc[cb][r] + cnr[cb][r], 0.f);
                float dist = frcp(1.0f + sq);
                acc[cb][r] = dist;
                rsp += dist;
            }
        rsp += __shfl_xor(rsp, 16);
        rsp += __shfl_xor(rsp, 32);
        float invR = frcp(rsp);

        #pragma unroll
        for (int cb = 0; cb < 8; ++cb)
            #pragma unroll
            for (int r = 0; r < 4; ++r) csum[cb][r] += acc[cb][r] * invR;
    }

    #pragma unroll
    for (int cb = 0; cb < 8; ++cb)
        #pragma unroll
        for (int r = 0; r < 4; ++r) {
            float v = csum[cb][r];
            v += __shfl_xor(v, 1); v += __shfl_xor(v, 2);
            v += __shfl_xor(v, 4); v += __shfl_xor(v, 8);
            csum[cb][r] = v;
        }
    if (m == 0) {
        #pragma unroll
        for (int cb = 0; cb < 8; ++cb) {
            f32x4 v = {csum[cb][0], csum[cb][1], csum[cb][2], csum[cb][3]};
            *(f32x4*)&cl[wid * 128 + cb * 16 + g * 4] = v;
        }
    }
    __syncthreads();
    if (tid < 128) {
        float s = cl[tid] + cl[128 + tid] + cl[256 + tid] + cl[384 + tid];
        colsum_part[(size_t)blockIdx.x * 128 + tid] = s;   // [block][k] layout
    }

    // ---- fused reduce: last block computes invS/log2S
    __threadfence();                                   // release partials (device scope)
    if (tid == 0) isLast = (atomicAdd(counter, 1) == nblocks - 1);
    __syncthreads();
    if (isLast) {
        __threadfence();                               // acquire partials
        const int k = tid & 127, h = tid >> 7;
        float s = 0.f;
        for (int b = h; b < nblocks; b += 2)
            s += colsum_part[(size_t)b * 128 + k];     // coalesced across k
        red[h][k] = s;
        __syncthreads();
        if (tid < 128) {
            float tot = red[0][tid] + red[1][tid];
            invS[tid] = 1.0f / tot;
            lS[tid] = __log2f(tot);
        }
    }
}

// K2: recompute sq via transposed MFMA, write q, fused loss (R8 main loop,
// untouched) + fused last-block loss reduce -> out[0].
__global__ __launch_bounds__(256) void k2_q_loss(
        const float* __restrict__ embeds, const float* __restrict__ centers,
        const float* __restrict__ invS, const float* __restrict__ lS,
        float* __restrict__ q, float* __restrict__ losspart,
        int* __restrict__ counter, float* __restrict__ out, int nblocks)
{
    __shared__ bf16x8 blds[8][2][64];
    __shared__ float cnLDS[128], isLDS[128], lsLDS[128];
    __shared__ float lds4[4];
    __shared__ int isLast;
    const int tid = threadIdx.x, wid = tid >> 6, lane = tid & 63;
    const int m = lane & 15, g = lane >> 4;

    if (tid < 128) { isLDS[tid] = invS[tid]; lsLDS[tid] = lS[tid]; }
    stage_centers_T(centers, blds, cnLDS, wid, lane, m, g);  // has __syncthreads

    f32x4 cnr[8], isr[8], lsr[8];
    #pragma unroll
    for (int cb = 0; cb < 8; ++cb) {
        cnr[cb] = *(const f32x4*)&cnLDS[cb * 16 + g * 4];
        isr[cb] = *(const f32x4*)&isLDS[cb * 16 + g * 4];
        lsr[cb] = *(const f32x4*)&lsLDS[cb * 16 + g * 4];
    }

    float loss = 0.f;
    const int gwid = blockIdx.x * 4 + wid;
    const int nw = nblocks * 4;

    int t = gwid;
    f32x4 n0, n1, n2, n3;
    if (t < NTILES) {
        const float* src = embeds + (size_t)(t * 16 + m) * DIMS + g * 8;
        n0 = *(const f32x4*)src;       n1 = *(const f32x4*)(src + 4);
        n2 = *(const f32x4*)(src + 32); n3 = *(const f32x4*)(src + 36);
    }
    for (; t < NTILES; t += nw) {
        f32x4 c0 = n0, c1 = n1, c2 = n2, c3 = n3;
        int tn = t + nw;
        if (tn < NTILES) {
            const float* src = embeds + (size_t)(tn * 16 + m) * DIMS + g * 8;
            n0 = *(const f32x4*)src;       n1 = *(const f32x4*)(src + 4);
            n2 = *(const f32x4*)(src + 32); n3 = *(const f32x4*)(src + 36);
        }
        bf16x8 a0, a1;
        float en = 0.f;
        #pragma unroll
        for (int j = 0; j < 4; ++j) {
            float f0 = c0[j], f1 = c1[j], f2 = c2[j], f3 = c3[j];
            en += f0 * f0 + f1 * f1 + f2 * f2 + f3 * f3;
            a0[j] = f2bf(f0); a0[j + 4] = f2bf(f1);
            a1[j] = f2bf(f2); a1[j + 4] = f2bf(f3);
        }
        en += __shfl_xor(en, 16);
        en += __shfl_xor(en, 32);

        f32x4 acc[8];
        #pragma unroll
        for (int cb = 0; cb < 8; ++cb) {
            f32x4 a = {en, en, en, en};
            a = __builtin_amdgcn_mfma_f32_16x16x32_bf16(blds[cb][0][lane], a0, a, 0, 0, 0);
            a = __builtin_amdgcn_mfma_f32_16x16x32_bf16(blds[cb][1][lane], a1, a, 0, 0, 0);
            acc[cb] = a;
        }

        float rsp = 0.f;
        #pragma unroll
        for (int cb = 0; cb < 8; ++cb)
            #pragma unroll
            for (int r = 0; r < 4; ++r) {
                float sq = fmaxf(acc[cb][r] + cnr[cb][r], 0.f);
                float dist = frcp(1.0f + sq);
                acc[cb][r] = dist;
                rsp += dist;
            }
        rsp += __shfl_xor(rsp, 16);
        rsp += __shfl_xor(rsp, 32);
        float invR = frcp(rsp);

        float Wp = 0.f;
        float* qrow = q + (size_t)(t * 16 + m) * KC + g * 4;
        #pragma unroll
        for (int cb = 0; cb < 8; ++cb)
            #pragma unroll
            for (int r = 0; r < 4; ++r) {
                float qv = acc[cb][r] * invR;
                acc[cb][r] = qv;
                qrow[cb * 16 + r] = qv;
                Wp += qv * qv * isr[cb][r];
            }
        Wp += __shfl_xor(Wp, 16);
        Wp += __shfl_xor(Wp, 32);
        float iw = frcp(Wp);
        float lw = __log2f(Wp);

        #pragma unroll
        for (int cb = 0; cb < 8; ++cb)
            #pragma unroll
            for (int r = 0; r < 4; ++r) {
                float qv = acc[cb][r];
                float w = qv * qv * isr[cb][r];
                loss += w * iw * (__log2f(qv) - lsr[cb][r] - lw);
            }
    }

    loss += __shfl_xor(loss, 1);  loss += __shfl_xor(loss, 2);
    loss += __shfl_xor(loss, 4);  loss += __shfl_xor(loss, 8);
    loss += __shfl_xor(loss, 16); loss += __shfl_xor(loss, 32);
    if (lane == 0) lds4[wid] = loss;
    __syncthreads();
    if (tid == 0) losspart[blockIdx.x] = lds4[0] + lds4[1] + lds4[2] + lds4[3];

    // ---- fused reduce: last block sums loss partials -> out[0]
    __threadfence();
    if (tid == 0) isLast = (atomicAdd(counter, 1) == nblocks - 1);
    __syncthreads();
    if (isLast) {
        __threadfence();
        float s = 0.f;
        for (int b = tid; b < nblocks; b += 256) s += losspart[b];
        s += __shfl_xor(s, 1);  s += __shfl_xor(s, 2);  s += __shfl_xor(s, 4);
        s += __shfl_xor(s, 8);  s += __shfl_xor(s, 16); s += __shfl_xor(s, 32);
        if (lane == 0) lds4[wid] = s;
        __syncthreads();
        if (tid == 0) {
            float tot = lds4[0] + lds4[1] + lds4[2] + lds4[3];
            out[0] = (float)((double)tot * 0.6931471805599453 /
                             (double)((size_t)NROWS * KC));
        }
    }
}

extern "C" void kernel_launch(void* const* d_in, const int* in_sizes, int n_in,
                              void* d_out, int out_size, void* d_ws, size_t ws_size,
                              hipStream_t stream)
{
    const float* embeds  = (const float*)d_in[0];
    const float* centers = (const float*)d_in[1];
    float* out  = (float*)d_out;
    float* qbuf = out + 1;
    float* ws   = (float*)d_ws;

    const int GB1 = 512, GB2 = 512;       // R8 grids, untouched
    float* colsum_part = ws;                          // GB1*128 ([block][k])
    float* invS  = ws + (size_t)GB1 * 128;            // 128
    float* lS    = invS + 128;                        // 128
    float* lpart = lS + 128;                          // GB2
    int*   ctrs  = (int*)(lpart + GB2);               // 2 counters

    hipMemsetAsync(ctrs, 0, 2 * sizeof(int), stream);
    hipLaunchKernelGGL(k1_colsum, dim3(GB1), dim3(256), 0, stream,
                       embeds, centers, colsum_part, invS, lS, ctrs + 0, GB1);
    hipLaunchKernelGGL(k2_q_loss, dim3(GB2), dim3(256), 0, stream,
                       embeds, centers, invS, lS, qbuf, lpart, ctrs + 1, out, GB2);
}

// Round 15
// 196.896 us; speedup vs baseline: 1.5933x; 1.5933x over previous
//
#include <hip/hip_runtime.h>
#include <stdint.h>
#include <stddef.h>

typedef __attribute__((ext_vector_type(8))) short bf16x8;
typedef __attribute__((ext_vector_type(4))) float f32x4;

#define NROWS 400000
#define KC 128
#define DIMS 64
#define NTILES (NROWS / 16)

__device__ __forceinline__ short f2bf(float f) {
    union { float f; uint32_t u; } v; v.f = f;
    uint32_t u = v.u;
    uint32_t r = (u + 0x7FFFu + ((u >> 16) & 1u)) >> 16;  // RNE, finite inputs
    return (short)r;
}

__device__ __forceinline__ float frcp(float x) { return __builtin_amdgcn_rcpf(x); }

// Stage -2*centers bf16 A-fragments into LDS + center norms into cnLDS. (R8)
__device__ __forceinline__ void stage_centers_T(
        const float* __restrict__ centers, bf16x8 (*blds)[2][64],
        float* cnLDS, int wid, int lane, int m, int g)
{
    #pragma unroll
    for (int cb = 0; cb < 8; ++cb) {
        float cacc = 0.f;
        bf16x8 bfr[2];
        #pragma unroll
        for (int h = 0; h < 2; ++h) {
            const float* src = centers + (size_t)(cb * 16 + m) * DIMS + h * 32 + g * 8;
            f32x4 c0 = *(const f32x4*)src;
            f32x4 c1 = *(const f32x4*)(src + 4);
            bf16x8 b;
            #pragma unroll
            for (int j = 0; j < 4; ++j) {
                float f0 = c0[j], f1 = c1[j];
                cacc += f0 * f0 + f1 * f1;
                b[j]     = f2bf(-2.0f * f0);
                b[j + 4] = f2bf(-2.0f * f1);
            }
            bfr[h] = b;
        }
        cacc += __shfl_xor(cacc, 16);
        cacc += __shfl_xor(cacc, 32);
        if (wid == 0) {
            blds[cb][0][lane] = bfr[0];
            blds[cb][1][lane] = bfr[1];
            if (g == 0) cnLDS[cb * 16 + m] = cacc;
        }
    }
    __syncthreads();
}

// K1: colsum of q (R8 main loop) + fused last-block reduce -> invS/log2S.
// Safe to fuse here: K1 dirties only 512B/block in L2, so the device fence
// is cheap (unlike K2's 205MB q stream -> R14 catastrophe).
__global__ __launch_bounds__(256) void k1_colsum(
        const float* __restrict__ embeds, const float* __restrict__ centers,
        float* __restrict__ colsum_part, float* __restrict__ invS,
        float* __restrict__ lS, int* __restrict__ counter, int nblocks)
{
    __shared__ bf16x8 blds[8][2][64];
    __shared__ float cnLDS[128];
    __shared__ float cl[4 * 128];
    __shared__ float red[2][128];
    __shared__ int isLast;
    const int tid = threadIdx.x, wid = tid >> 6, lane = tid & 63;
    const int m = lane & 15, g = lane >> 4;

    stage_centers_T(centers, blds, cnLDS, wid, lane, m, g);

    f32x4 cnr[8];
    #pragma unroll
    for (int cb = 0; cb < 8; ++cb) cnr[cb] = *(const f32x4*)&cnLDS[cb * 16 + g * 4];

    float csum[8][4];
    #pragma unroll
    for (int cb = 0; cb < 8; ++cb)
        #pragma unroll
        for (int r = 0; r < 4; ++r) csum[cb][r] = 0.f;

    const int gwid = blockIdx.x * 4 + wid;
    const int nw = nblocks * 4;

    int t = gwid;
    f32x4 n0, n1, n2, n3;
    if (t < NTILES) {
        const float* src = embeds + (size_t)(t * 16 + m) * DIMS + g * 8;
        n0 = *(const f32x4*)src;       n1 = *(const f32x4*)(src + 4);
        n2 = *(const f32x4*)(src + 32); n3 = *(const f32x4*)(src + 36);
    }
    for (; t < NTILES; t += nw) {
        f32x4 c0 = n0, c1 = n1, c2 = n2, c3 = n3;
        int tn = t + nw;
        if (tn < NTILES) {
            const float* src = embeds + (size_t)(tn * 16 + m) * DIMS + g * 8;
            n0 = *(const f32x4*)src;       n1 = *(const f32x4*)(src + 4);
            n2 = *(const f32x4*)(src + 32); n3 = *(const f32x4*)(src + 36);
        }
        bf16x8 a0, a1;
        float en = 0.f;
        #pragma unroll
        for (int j = 0; j < 4; ++j) {
            float f0 = c0[j], f1 = c1[j], f2 = c2[j], f3 = c3[j];
            en += f0 * f0 + f1 * f1 + f2 * f2 + f3 * f3;
            a0[j] = f2bf(f0); a0[j + 4] = f2bf(f1);
            a1[j] = f2bf(f2); a1[j + 4] = f2bf(f3);
        }
        en += __shfl_xor(en, 16);
        en += __shfl_xor(en, 32);

        f32x4 acc[8];
        #pragma unroll
        for (int cb = 0; cb < 8; ++cb) {
            f32x4 a = {en, en, en, en};
            a = __builtin_amdgcn_mfma_f32_16x16x32_bf16(blds[cb][0][lane], a0, a, 0, 0, 0);
            a = __builtin_amdgcn_mfma_f32_16x16x32_bf16(blds[cb][1][lane], a1, a, 0, 0, 0);
            acc[cb] = a;
        }

        float rsp = 0.f;
        #pragma unroll
        for (int cb = 0; cb < 8; ++cb)
            #pragma unroll
            for (int r = 0; r < 4; ++r) {
                float sq = fmaxf(acc[cb][r] + cnr[cb][r], 0.f);
                float dist = frcp(1.0f + sq);
                acc[cb][r] = dist;
                rsp += dist;
            }
        rsp += __shfl_xor(rsp, 16);
        rsp += __shfl_xor(rsp, 32);
        float invR = frcp(rsp);

        #pragma unroll
        for (int cb = 0; cb < 8; ++cb)
            #pragma unroll
            for (int r = 0; r < 4; ++r) csum[cb][r] += acc[cb][r] * invR;
    }

    #pragma unroll
    for (int cb = 0; cb < 8; ++cb)
        #pragma unroll
        for (int r = 0; r < 4; ++r) {
            float v = csum[cb][r];
            v += __shfl_xor(v, 1); v += __shfl_xor(v, 2);
            v += __shfl_xor(v, 4); v += __shfl_xor(v, 8);
            csum[cb][r] = v;
        }
    if (m == 0) {
        #pragma unroll
        for (int cb = 0; cb < 8; ++cb) {
            f32x4 v = {csum[cb][0], csum[cb][1], csum[cb][2], csum[cb][3]};
            *(f32x4*)&cl[wid * 128 + cb * 16 + g * 4] = v;
        }
    }
    __syncthreads();
    if (tid < 128) {
        float s = cl[tid] + cl[128 + tid] + cl[256 + tid] + cl[384 + tid];
        colsum_part[(size_t)blockIdx.x * 128 + tid] = s;   // [block][k]: tail-coalesced
    }

    // fused reduce: last block -> invS / log2S
    __threadfence();
    if (tid == 0) isLast = (atomicAdd(counter, 1) == nblocks - 1);
    __syncthreads();
    if (isLast) {
        __threadfence();
        const int k = tid & 127, h = tid >> 7;
        float s = 0.f;
        for (int b = h; b < nblocks; b += 2)
            s += colsum_part[(size_t)b * 128 + k];
        red[h][k] = s;
        __syncthreads();
        if (tid < 128) {
            float tot = red[0][tid] + red[1][tid];
            invS[tid] = 1.0f / tot;
            lS[tid] = __log2f(tot);
        }
    }
}

// K2: byte-identical to R8 (97.6 us codegen). No fences, no atomics.
__global__ __launch_bounds__(256) void k2_q_loss(
        const float* __restrict__ embeds, const float* __restrict__ centers,
        const float* __restrict__ invS, const float* __restrict__ lS,
        float* __restrict__ q, float* __restrict__ losspart, int nblocks)
{
    __shared__ bf16x8 blds[8][2][64];
    __shared__ float cnLDS[128], isLDS[128], lsLDS[128];
    __shared__ float lds4[4];
    const int tid = threadIdx.x, wid = tid >> 6, lane = tid & 63;
    const int m = lane & 15, g = lane >> 4;

    if (tid < 128) { isLDS[tid] = invS[tid]; lsLDS[tid] = lS[tid]; }
    stage_centers_T(centers, blds, cnLDS, wid, lane, m, g);  // has __syncthreads

    f32x4 cnr[8], isr[8], lsr[8];
    #pragma unroll
    for (int cb = 0; cb < 8; ++cb) {
        cnr[cb] = *(const f32x4*)&cnLDS[cb * 16 + g * 4];
        isr[cb] = *(const f32x4*)&isLDS[cb * 16 + g * 4];
        lsr[cb] = *(const f32x4*)&lsLDS[cb * 16 + g * 4];
    }

    float loss = 0.f;
    const int gwid = blockIdx.x * 4 + wid;
    const int nw = nblocks * 4;

    int t = gwid;
    f32x4 n0, n1, n2, n3;
    if (t < NTILES) {
        const float* src = embeds + (size_t)(t * 16 + m) * DIMS + g * 8;
        n0 = *(const f32x4*)src;       n1 = *(const f32x4*)(src + 4);
        n2 = *(const f32x4*)(src + 32); n3 = *(const f32x4*)(src + 36);
    }
    for (; t < NTILES; t += nw) {
        f32x4 c0 = n0, c1 = n1, c2 = n2, c3 = n3;
        int tn = t + nw;
        if (tn < NTILES) {
            const float* src = embeds + (size_t)(tn * 16 + m) * DIMS + g * 8;
            n0 = *(const f32x4*)src;       n1 = *(const f32x4*)(src + 4);
            n2 = *(const f32x4*)(src + 32); n3 = *(const f32x4*)(src + 36);
        }
        bf16x8 a0, a1;
        float en = 0.f;
        #pragma unroll
        for (int j = 0; j < 4; ++j) {
            float f0 = c0[j], f1 = c1[j], f2 = c2[j], f3 = c3[j];
            en += f0 * f0 + f1 * f1 + f2 * f2 + f3 * f3;
            a0[j] = f2bf(f0); a0[j + 4] = f2bf(f1);
            a1[j] = f2bf(f2); a1[j + 4] = f2bf(f3);
        }
        en += __shfl_xor(en, 16);
        en += __shfl_xor(en, 32);

        f32x4 acc[8];
        #pragma unroll
        for (int cb = 0; cb < 8; ++cb) {
            f32x4 a = {en, en, en, en};
            a = __builtin_amdgcn_mfma_f32_16x16x32_bf16(blds[cb][0][lane], a0, a, 0, 0, 0);
            a = __builtin_amdgcn_mfma_f32_16x16x32_bf16(blds[cb][1][lane], a1, a, 0, 0, 0);
            acc[cb] = a;
        }

        float rsp = 0.f;
        #pragma unroll
        for (int cb = 0; cb < 8; ++cb)
            #pragma unroll
            for (int r = 0; r < 4; ++r) {
                float sq = fmaxf(acc[cb][r] + cnr[cb][r], 0.f);
                float dist = frcp(1.0f + sq);
                acc[cb][r] = dist;
                rsp += dist;
            }
        rsp += __shfl_xor(rsp, 16);
        rsp += __shfl_xor(rsp, 32);
        float invR = frcp(rsp);

        float Wp = 0.f;
        float* qrow = q + (size_t)(t * 16 + m) * KC + g * 4;
        #pragma unroll
        for (int cb = 0; cb < 8; ++cb)
            #pragma unroll
            for (int r = 0; r < 4; ++r) {
                float qv = acc[cb][r] * invR;
                acc[cb][r] = qv;
                qrow[cb * 16 + r] = qv;
                Wp += qv * qv * isr[cb][r];
            }
        Wp += __shfl_xor(Wp, 16);
        Wp += __shfl_xor(Wp, 32);
        float iw = frcp(Wp);
        float lw = __log2f(Wp);

        #pragma unroll
        for (int cb = 0; cb < 8; ++cb)
            #pragma unroll
            for (int r = 0; r < 4; ++r) {
                float qv = acc[cb][r];
                float w = qv * qv * isr[cb][r];
                loss += w * iw * (__log2f(qv) - lsr[cb][r] - lw);
            }
    }

    loss += __shfl_xor(loss, 1);  loss += __shfl_xor(loss, 2);
    loss += __shfl_xor(loss, 4);  loss += __shfl_xor(loss, 8);
    loss += __shfl_xor(loss, 16); loss += __shfl_xor(loss, 32);
    if (lane == 0) lds4[wid] = loss;
    __syncthreads();
    if (tid == 0) losspart[blockIdx.x] = lds4[0] + lds4[1] + lds4[2] + lds4[3];
}

// K2b: final loss reduce; convert log2 -> ln (R8)
__global__ __launch_bounds__(1024) void k2b_final(
        const float* __restrict__ losspart, int nb, float* __restrict__ out)
{
    __shared__ float lds[16];
    const int tid = threadIdx.x;
    float s = 0.f;
    for (int b = tid; b < nb; b += 1024) s += losspart[b];
    s += __shfl_xor(s, 1);  s += __shfl_xor(s, 2);  s += __shfl_xor(s, 4);
    s += __shfl_xor(s, 8);  s += __shfl_xor(s, 16); s += __shfl_xor(s, 32);
    if ((tid & 63) == 0) lds[tid >> 6] = s;
    __syncthreads();
    if (tid == 0) {
        float tot = 0.f;
        #pragma unroll
        for (int i = 0; i < 16; ++i) tot += lds[i];
        out[0] = (float)((double)tot * 0.6931471805599453 /
                         (double)((size_t)NROWS * KC));
    }
}

extern "C" void kernel_launch(void* const* d_in, const int* in_sizes, int n_in,
                              void* d_out, int out_size, void* d_ws, size_t ws_size,
                              hipStream_t stream)
{
    const float* embeds  = (const float*)d_in[0];
    const float* centers = (const float*)d_in[1];
    float* out  = (float*)d_out;
    float* qbuf = out + 1;
    float* ws   = (float*)d_ws;

    const int GB1 = 512, GB2 = 512;
    float* colsum_part = ws;                          // GB1*128 ([block][k])
    float* invS  = ws + (size_t)GB1 * 128;            // 128
    float* lS    = invS + 128;                        // 128
    float* lpart = lS + 128;                          // GB2
    int*   ctr   = (int*)(lpart + GB2);               // 1 counter

    hipMemsetAsync(ctr, 0, sizeof(int), stream);
    hipLaunchKernelGGL(k1_colsum, dim3(GB1), dim3(256), 0, stream,
                       embeds, centers, colsum_part, invS, lS, ctr, GB1);
    hipLaunchKernelGGL(k2_q_loss, dim3(GB2), dim3(256), 0, stream,
                       embeds, centers, invS, lS, qbuf, lpart, GB2);
    hipLaunchKernelGGL(k2b_final, dim3(1), dim3(1024), 0, stream,
                       lpart, GB2, out);
}

// Round 16
// 112.830 us; speedup vs baseline: 2.7805x; 1.7451x over previous
//
#include <hip/hip_runtime.h>
#include <stdint.h>
#include <stddef.h>

typedef __attribute__((ext_vector_type(8))) short bf16x8;
typedef __attribute__((ext_vector_type(4))) float f32x4;

#define NROWS 400000
#define KC 128
#define DIMS 64
#define NTILES (NROWS / 16)

__device__ __forceinline__ short f2bf(float f) {
    union { float f; uint32_t u; } v; v.f = f;
    uint32_t u = v.u;
    uint32_t r = (u + 0x7FFFu + ((u >> 16) & 1u)) >> 16;  // RNE, finite inputs
    return (short)r;
}

__device__ __forceinline__ float frcp(float x) { return __builtin_amdgcn_rcpf(x); }

// Stage -2*centers bf16 A-fragments into LDS + center norms into cnLDS. (R8)
__device__ __forceinline__ void stage_centers_T(
        const float* __restrict__ centers, bf16x8 (*blds)[2][64],
        float* cnLDS, int wid, int lane, int m, int g)
{
    #pragma unroll
    for (int cb = 0; cb < 8; ++cb) {
        float cacc = 0.f;
        bf16x8 bfr[2];
        #pragma unroll
        for (int h = 0; h < 2; ++h) {
            const float* src = centers + (size_t)(cb * 16 + m) * DIMS + h * 32 + g * 8;
            f32x4 c0 = *(const f32x4*)src;
            f32x4 c1 = *(const f32x4*)(src + 4);
            bf16x8 b;
            #pragma unroll
            for (int j = 0; j < 4; ++j) {
                float f0 = c0[j], f1 = c1[j];
                cacc += f0 * f0 + f1 * f1;
                b[j]     = f2bf(-2.0f * f0);
                b[j + 4] = f2bf(-2.0f * f1);
            }
            bfr[h] = b;
        }
        cacc += __shfl_xor(cacc, 16);
        cacc += __shfl_xor(cacc, 32);
        if (wid == 0) {
            blds[cb][0][lane] = bfr[0];
            blds[cb][1][lane] = bfr[1];
            if (g == 0) cnLDS[cb * 16 + m] = cacc;
        }
    }
    __syncthreads();
}

// K1: column sums of q (R8, byte-identical). No fences, no atomics.
__global__ __launch_bounds__(256) void k1_colsum(
        const float* __restrict__ embeds, const float* __restrict__ centers,
        float* __restrict__ colsum_part, int nblocks)
{
    __shared__ bf16x8 blds[8][2][64];
    __shared__ float cnLDS[128];
    __shared__ float cl[4 * 128];
    const int tid = threadIdx.x, wid = tid >> 6, lane = tid & 63;
    const int m = lane & 15, g = lane >> 4;

    stage_centers_T(centers, blds, cnLDS, wid, lane, m, g);

    f32x4 cnr[8];
    #pragma unroll
    for (int cb = 0; cb < 8; ++cb) cnr[cb] = *(const f32x4*)&cnLDS[cb * 16 + g * 4];

    float csum[8][4];
    #pragma unroll
    for (int cb = 0; cb < 8; ++cb)
        #pragma unroll
        for (int r = 0; r < 4; ++r) csum[cb][r] = 0.f;

    const int gwid = blockIdx.x * 4 + wid;
    const int nw = nblocks * 4;

    int t = gwid;
    f32x4 n0, n1, n2, n3;
    if (t < NTILES) {
        const float* src = embeds + (size_t)(t * 16 + m) * DIMS + g * 8;
        n0 = *(const f32x4*)src;       n1 = *(const f32x4*)(src + 4);
        n2 = *(const f32x4*)(src + 32); n3 = *(const f32x4*)(src + 36);
    }
    for (; t < NTILES; t += nw) {
        f32x4 c0 = n0, c1 = n1, c2 = n2, c3 = n3;
        int tn = t + nw;
        if (tn < NTILES) {
            const float* src = embeds + (size_t)(tn * 16 + m) * DIMS + g * 8;
            n0 = *(const f32x4*)src;       n1 = *(const f32x4*)(src + 4);
            n2 = *(const f32x4*)(src + 32); n3 = *(const f32x4*)(src + 36);
        }
        bf16x8 a0, a1;
        float en = 0.f;
        #pragma unroll
        for (int j = 0; j < 4; ++j) {
            float f0 = c0[j], f1 = c1[j], f2 = c2[j], f3 = c3[j];
            en += f0 * f0 + f1 * f1 + f2 * f2 + f3 * f3;
            a0[j] = f2bf(f0); a0[j + 4] = f2bf(f1);
            a1[j] = f2bf(f2); a1[j + 4] = f2bf(f3);
        }
        en += __shfl_xor(en, 16);
        en += __shfl_xor(en, 32);

        f32x4 acc[8];
        #pragma unroll
        for (int cb = 0; cb < 8; ++cb) {
            f32x4 a = {en, en, en, en};
            a = __builtin_amdgcn_mfma_f32_16x16x32_bf16(blds[cb][0][lane], a0, a, 0, 0, 0);
            a = __builtin_amdgcn_mfma_f32_16x16x32_bf16(blds[cb][1][lane], a1, a, 0, 0, 0);
            acc[cb] = a;
        }

        float rsp = 0.f;
        #pragma unroll
        for (int cb = 0; cb < 8; ++cb)
            #pragma unroll
            for (int r = 0; r < 4; ++r) {
                float sq = fmaxf(acc[cb][r] + cnr[cb][r], 0.f);
                float dist = frcp(1.0f + sq);
                acc[cb][r] = dist;
                rsp += dist;
            }
        rsp += __shfl_xor(rsp, 16);
        rsp += __shfl_xor(rsp, 32);
        float invR = frcp(rsp);

        #pragma unroll
        for (int cb = 0; cb < 8; ++cb)
            #pragma unroll
            for (int r = 0; r < 4; ++r) csum[cb][r] += acc[cb][r] * invR;
    }

    #pragma unroll
    for (int cb = 0; cb < 8; ++cb)
        #pragma unroll
        for (int r = 0; r < 4; ++r) {
            float v = csum[cb][r];
            v += __shfl_xor(v, 1); v += __shfl_xor(v, 2);
            v += __shfl_xor(v, 4); v += __shfl_xor(v, 8);
            csum[cb][r] = v;
        }
    if (m == 0) {
        #pragma unroll
        for (int cb = 0; cb < 8; ++cb) {
            f32x4 v = {csum[cb][0], csum[cb][1], csum[cb][2], csum[cb][3]};
            *(f32x4*)&cl[wid * 128 + cb * 16 + g * 4] = v;
        }
    }
    __syncthreads();
    if (tid < 128) {
        float s = cl[tid] + cl[128 + tid] + cl[256 + tid] + cl[384 + tid];
        colsum_part[(size_t)tid * nblocks + blockIdx.x] = s;   // transposed
    }
}

// K1b: 128 blocks, block k reduces contiguous row k -> invS[k], log2S[k] (R8)
__global__ __launch_bounds__(256) void k1b_reduce(
        const float* __restrict__ part, float* __restrict__ invS,
        float* __restrict__ lS, int nb)
{
    __shared__ float lds[4];
    const int k = blockIdx.x;
    const int tid = threadIdx.x, wid = tid >> 6, lane = tid & 63;
    float s = 0.f;
    for (int b = tid; b < nb; b += 256) s += part[(size_t)k * nb + b];
    s += __shfl_xor(s, 1);  s += __shfl_xor(s, 2);  s += __shfl_xor(s, 4);
    s += __shfl_xor(s, 8);  s += __shfl_xor(s, 16); s += __shfl_xor(s, 32);
    if (lane == 0) lds[wid] = s;
    __syncthreads();
    if (tid == 0) {
        float tot = lds[0] + lds[1] + lds[2] + lds[3];
        invS[k] = 1.0f / tot;
        lS[k] = __log2f(tot);
    }
}

// K2: recompute sq via transposed MFMA, write q, fused loss (R8, byte-identical).
__global__ __launch_bounds__(256) void k2_q_loss(
        const float* __restrict__ embeds, const float* __restrict__ centers,
        const float* __restrict__ invS, const float* __restrict__ lS,
        float* __restrict__ q, float* __restrict__ losspart, int nblocks)
{
    __shared__ bf16x8 blds[8][2][64];
    __shared__ float cnLDS[128], isLDS[128], lsLDS[128];
    __shared__ float lds4[4];
    const int tid = threadIdx.x, wid = tid >> 6, lane = tid & 63;
    const int m = lane & 15, g = lane >> 4;

    if (tid < 128) { isLDS[tid] = invS[tid]; lsLDS[tid] = lS[tid]; }
    stage_centers_T(centers, blds, cnLDS, wid, lane, m, g);  // has __syncthreads

    f32x4 cnr[8], isr[8], lsr[8];
    #pragma unroll
    for (int cb = 0; cb < 8; ++cb) {
        cnr[cb] = *(const f32x4*)&cnLDS[cb * 16 + g * 4];
        isr[cb] = *(const f32x4*)&isLDS[cb * 16 + g * 4];
        lsr[cb] = *(const f32x4*)&lsLDS[cb * 16 + g * 4];
    }

    float loss = 0.f;
    const int gwid = blockIdx.x * 4 + wid;
    const int nw = nblocks * 4;

    int t = gwid;
    f32x4 n0, n1, n2, n3;
    if (t < NTILES) {
        const float* src = embeds + (size_t)(t * 16 + m) * DIMS + g * 8;
        n0 = *(const f32x4*)src;       n1 = *(const f32x4*)(src + 4);
        n2 = *(const f32x4*)(src + 32); n3 = *(const f32x4*)(src + 36);
    }
    for (; t < NTILES; t += nw) {
        f32x4 c0 = n0, c1 = n1, c2 = n2, c3 = n3;
        int tn = t + nw;
        if (tn < NTILES) {
            const float* src = embeds + (size_t)(tn * 16 + m) * DIMS + g * 8;
            n0 = *(const f32x4*)src;       n1 = *(const f32x4*)(src + 4);
            n2 = *(const f32x4*)(src + 32); n3 = *(const f32x4*)(src + 36);
        }
        bf16x8 a0, a1;
        float en = 0.f;
        #pragma unroll
        for (int j = 0; j < 4; ++j) {
            float f0 = c0[j], f1 = c1[j], f2 = c2[j], f3 = c3[j];
            en += f0 * f0 + f1 * f1 + f2 * f2 + f3 * f3;
            a0[j] = f2bf(f0); a0[j + 4] = f2bf(f1);
            a1[j] = f2bf(f2); a1[j + 4] = f2bf(f3);
        }
        en += __shfl_xor(en, 16);
        en += __shfl_xor(en, 32);

        f32x4 acc[8];
        #pragma unroll
        for (int cb = 0; cb < 8; ++cb) {
            f32x4 a = {en, en, en, en};
            a = __builtin_amdgcn_mfma_f32_16x16x32_bf16(blds[cb][0][lane], a0, a, 0, 0, 0);
            a = __builtin_amdgcn_mfma_f32_16x16x32_bf16(blds[cb][1][lane], a1, a, 0, 0, 0);
            acc[cb] = a;
        }

        float rsp = 0.f;
        #pragma unroll
        for (int cb = 0; cb < 8; ++cb)
            #pragma unroll
            for (int r = 0; r < 4; ++r) {
                float sq = fmaxf(acc[cb][r] + cnr[cb][r], 0.f);
                float dist = frcp(1.0f + sq);
                acc[cb][r] = dist;
                rsp += dist;
            }
        rsp += __shfl_xor(rsp, 16);
        rsp += __shfl_xor(rsp, 32);
        float invR = frcp(rsp);

        float Wp = 0.f;
        float* qrow = q + (size_t)(t * 16 + m) * KC + g * 4;
        #pragma unroll
        for (int cb = 0; cb < 8; ++cb)
            #pragma unroll
            for (int r = 0; r < 4; ++r) {
                float qv = acc[cb][r] * invR;
                acc[cb][r] = qv;
                qrow[cb * 16 + r] = qv;
                Wp += qv * qv * isr[cb][r];
            }
        Wp += __shfl_xor(Wp, 16);
        Wp += __shfl_xor(Wp, 32);
        float iw = frcp(Wp);
        float lw = __log2f(Wp);

        #pragma unroll
        for (int cb = 0; cb < 8; ++cb)
            #pragma unroll
            for (int r = 0; r < 4; ++r) {
                float qv = acc[cb][r];
                float w = qv * qv * isr[cb][r];
                loss += w * iw * (__log2f(qv) - lsr[cb][r] - lw);
            }
    }

    loss += __shfl_xor(loss, 1);  loss += __shfl_xor(loss, 2);
    loss += __shfl_xor(loss, 4);  loss += __shfl_xor(loss, 8);
    loss += __shfl_xor(loss, 16); loss += __shfl_xor(loss, 32);
    if (lane == 0) lds4[wid] = loss;
    __syncthreads();
    if (tid == 0) losspart[blockIdx.x] = lds4[0] + lds4[1] + lds4[2] + lds4[3];
}

// K2b: final loss reduce; convert log2 -> ln (R8)
__global__ __launch_bounds__(1024) void k2b_final(
        const float* __restrict__ losspart, int nb, float* __restrict__ out)
{
    __shared__ float lds[16];
    const int tid = threadIdx.x;
    float s = 0.f;
    for (int b = tid; b < nb; b += 1024) s += losspart[b];
    s += __shfl_xor(s, 1);  s += __shfl_xor(s, 2);  s += __shfl_xor(s, 4);
    s += __shfl_xor(s, 8);  s += __shfl_xor(s, 16); s += __shfl_xor(s, 32);
    if ((tid & 63) == 0) lds[tid >> 6] = s;
    __syncthreads();
    if (tid == 0) {
        float tot = 0.f;
        #pragma unroll
        for (int i = 0; i < 16; ++i) tot += lds[i];
        out[0] = (float)((double)tot * 0.6931471805599453 /
                         (double)((size_t)NROWS * KC));
    }
}

extern "C" void kernel_launch(void* const* d_in, const int* in_sizes, int n_in,
                              void* d_out, int out_size, void* d_ws, size_t ws_size,
                              hipStream_t stream)
{
    const float* embeds  = (const float*)d_in[0];
    const float* centers = (const float*)d_in[1];
    float* out  = (float*)d_out;
    float* qbuf = out + 1;
    float* ws   = (float*)d_ws;

    // SINGLE CHANGE vs R8: grids 512 -> 1024. If natural VGPR <= 128 (R15
    // measured 108 for K1-with-tail), 4 blocks/CU become resident; else the
    // block-strided slices queue and drain (bounded, ~neutral).
    int GB1 = 1024, GB2 = 1024;
    size_t need = ((size_t)GB1 * 128 + 256 + (size_t)GB2) * sizeof(float);
    if (need > ws_size) { GB1 = 512; GB2 = 512; }

    float* colsum_part = ws;                          // 128 * GB1 (transposed)
    float* invS  = ws + (size_t)GB1 * 128;            // 128
    float* lS    = invS + 128;                        // 128
    float* lpart = lS + 128;                          // GB2

    hipLaunchKernelGGL(k1_colsum, dim3(GB1), dim3(256), 0, stream,
                       embeds, centers, colsum_part, GB1);
    hipLaunchKernelGGL(k1b_reduce, dim3(128), dim3(256), 0, stream,
                       colsum_part, invS, lS, GB1);
    hipLaunchKernelGGL(k2_q_loss, dim3(GB2), dim3(256), 0, stream,
                       embeds, centers, invS, lS, qbuf, lpart, GB2);
    hipLaunchKernelGGL(k2b_final, dim3(1), dim3(1024), 0, stream,
                       lpart, GB2, out);
}

// Round 17
// 105.225 us; speedup vs baseline: 2.9815x; 1.0723x over previous
//
#include <hip/hip_runtime.h>
#include <stdint.h>
#include <stddef.h>

typedef __attribute__((ext_vector_type(8))) short bf16x8;
typedef __attribute__((ext_vector_type(4))) float f32x4;

#define NROWS 400000
#define KC 128
#define DIMS 64
#define NTILES (NROWS / 16)

__device__ __forceinline__ short f2bf(float f) {
    union { float f; uint32_t u; } v; v.f = f;
    uint32_t u = v.u;
    uint32_t r = (u + 0x7FFFu + ((u >> 16) & 1u)) >> 16;  // RNE, finite inputs
    return (short)r;
}

__device__ __forceinline__ float frcp(float x) { return __builtin_amdgcn_rcpf(x); }

// Stage -2*centers bf16 A-fragments into LDS + center norms into cnLDS. (R8)
__device__ __forceinline__ void stage_centers_T(
        const float* __restrict__ centers, bf16x8 (*blds)[2][64],
        float* cnLDS, int wid, int lane, int m, int g)
{
    #pragma unroll
    for (int cb = 0; cb < 8; ++cb) {
        float cacc = 0.f;
        bf16x8 bfr[2];
        #pragma unroll
        for (int h = 0; h < 2; ++h) {
            const float* src = centers + (size_t)(cb * 16 + m) * DIMS + h * 32 + g * 8;
            f32x4 c0 = *(const f32x4*)src;
            f32x4 c1 = *(const f32x4*)(src + 4);
            bf16x8 b;
            #pragma unroll
            for (int j = 0; j < 4; ++j) {
                float f0 = c0[j], f1 = c1[j];
                cacc += f0 * f0 + f1 * f1;
                b[j]     = f2bf(-2.0f * f0);
                b[j + 4] = f2bf(-2.0f * f1);
            }
            bfr[h] = b;
        }
        cacc += __shfl_xor(cacc, 16);
        cacc += __shfl_xor(cacc, 32);
        if (wid == 0) {
            blds[cb][0][lane] = bfr[0];
            blds[cb][1][lane] = bfr[1];
            if (g == 0) cnLDS[cb * 16 + m] = cacc;
        }
    }
    __syncthreads();
}

// K1: column sums of q. VGPR ~108 <= 128 -> 4 blocks/CU; grid 1024.
// rsp chain split 4-way (identical order to K2 -> bit-identical q).
__global__ __launch_bounds__(256) void k1_colsum(
        const float* __restrict__ embeds, const float* __restrict__ centers,
        float* __restrict__ colsum_part, int nblocks)
{
    __shared__ bf16x8 blds[8][2][64];
    __shared__ float cnLDS[128];
    __shared__ float cl[4 * 128];
    const int tid = threadIdx.x, wid = tid >> 6, lane = tid & 63;
    const int m = lane & 15, g = lane >> 4;

    stage_centers_T(centers, blds, cnLDS, wid, lane, m, g);

    f32x4 cnr[8];
    #pragma unroll
    for (int cb = 0; cb < 8; ++cb) cnr[cb] = *(const f32x4*)&cnLDS[cb * 16 + g * 4];

    float csum[8][4];
    #pragma unroll
    for (int cb = 0; cb < 8; ++cb)
        #pragma unroll
        for (int r = 0; r < 4; ++r) csum[cb][r] = 0.f;

    const int gwid = blockIdx.x * 4 + wid;
    const int nw = nblocks * 4;

    int t = gwid;
    f32x4 n0, n1, n2, n3;
    if (t < NTILES) {
        const float* src = embeds + (size_t)(t * 16 + m) * DIMS + g * 8;
        n0 = *(const f32x4*)src;       n1 = *(const f32x4*)(src + 4);
        n2 = *(const f32x4*)(src + 32); n3 = *(const f32x4*)(src + 36);
    }
    for (; t < NTILES; t += nw) {
        f32x4 c0 = n0, c1 = n1, c2 = n2, c3 = n3;
        int tn = t + nw;
        if (tn < NTILES) {
            const float* src = embeds + (size_t)(tn * 16 + m) * DIMS + g * 8;
            n0 = *(const f32x4*)src;       n1 = *(const f32x4*)(src + 4);
            n2 = *(const f32x4*)(src + 32); n3 = *(const f32x4*)(src + 36);
        }
        bf16x8 a0, a1;
        float en = 0.f;
        #pragma unroll
        for (int j = 0; j < 4; ++j) {
            float f0 = c0[j], f1 = c1[j], f2 = c2[j], f3 = c3[j];
            en += f0 * f0 + f1 * f1 + f2 * f2 + f3 * f3;
            a0[j] = f2bf(f0); a0[j + 4] = f2bf(f1);
            a1[j] = f2bf(f2); a1[j + 4] = f2bf(f3);
        }
        en += __shfl_xor(en, 16);
        en += __shfl_xor(en, 32);

        f32x4 acc[8];
        #pragma unroll
        for (int cb = 0; cb < 8; ++cb) {
            f32x4 a = {en, en, en, en};
            a = __builtin_amdgcn_mfma_f32_16x16x32_bf16(blds[cb][0][lane], a0, a, 0, 0, 0);
            a = __builtin_amdgcn_mfma_f32_16x16x32_bf16(blds[cb][1][lane], a1, a, 0, 0, 0);
            acc[cb] = a;
        }

        // 4 independent accumulation chains (8-deep each) instead of one 32-deep
        float rsp4[4] = {0.f, 0.f, 0.f, 0.f};
        #pragma unroll
        for (int cb = 0; cb < 8; ++cb)
            #pragma unroll
            for (int r = 0; r < 4; ++r) {
                float sq = fmaxf(acc[cb][r] + cnr[cb][r], 0.f);
                float dist = frcp(1.0f + sq);
                acc[cb][r] = dist;
                rsp4[r] += dist;
            }
        float rsp = (rsp4[0] + rsp4[1]) + (rsp4[2] + rsp4[3]);
        rsp += __shfl_xor(rsp, 16);
        rsp += __shfl_xor(rsp, 32);
        float invR = frcp(rsp);

        #pragma unroll
        for (int cb = 0; cb < 8; ++cb)
            #pragma unroll
            for (int r = 0; r < 4; ++r) csum[cb][r] += acc[cb][r] * invR;
    }

    #pragma unroll
    for (int cb = 0; cb < 8; ++cb)
        #pragma unroll
        for (int r = 0; r < 4; ++r) {
            float v = csum[cb][r];
            v += __shfl_xor(v, 1); v += __shfl_xor(v, 2);
            v += __shfl_xor(v, 4); v += __shfl_xor(v, 8);
            csum[cb][r] = v;
        }
    if (m == 0) {
        #pragma unroll
        for (int cb = 0; cb < 8; ++cb) {
            f32x4 v = {csum[cb][0], csum[cb][1], csum[cb][2], csum[cb][3]};
            *(f32x4*)&cl[wid * 128 + cb * 16 + g * 4] = v;
        }
    }
    __syncthreads();
    if (tid < 128) {
        float s = cl[tid] + cl[128 + tid] + cl[256 + tid] + cl[384 + tid];
        colsum_part[(size_t)tid * nblocks + blockIdx.x] = s;   // transposed
    }
}

// K1b: 128 blocks, block k reduces contiguous row k -> invS[k], log2S[k] (R8)
__global__ __launch_bounds__(256) void k1b_reduce(
        const float* __restrict__ part, float* __restrict__ invS,
        float* __restrict__ lS, int nb)
{
    __shared__ float lds[4];
    const int k = blockIdx.x;
    const int tid = threadIdx.x, wid = tid >> 6, lane = tid & 63;
    float s = 0.f;
    for (int b = tid; b < nb; b += 256) s += part[(size_t)k * nb + b];
    s += __shfl_xor(s, 1);  s += __shfl_xor(s, 2);  s += __shfl_xor(s, 4);
    s += __shfl_xor(s, 8);  s += __shfl_xor(s, 16); s += __shfl_xor(s, 32);
    if (lane == 0) lds[wid] = s;
    __syncthreads();
    if (tid == 0) {
        float tot = lds[0] + lds[1] + lds[2] + lds[3];
        invS[k] = 1.0f / tot;
        lS[k] = __log2f(tot);
    }
}

// K2: recompute sq via transposed MFMA, write q, fused loss. Grid 512
// (VGPR ~145 > 128 -> 2 blocks/CU). rsp/Wp/loss chains split 4-way.
__global__ __launch_bounds__(256) void k2_q_loss(
        const float* __restrict__ embeds, const float* __restrict__ centers,
        const float* __restrict__ invS, const float* __restrict__ lS,
        float* __restrict__ q, float* __restrict__ losspart, int nblocks)
{
    __shared__ bf16x8 blds[8][2][64];
    __shared__ float cnLDS[128], isLDS[128], lsLDS[128];
    __shared__ float lds4[4];
    const int tid = threadIdx.x, wid = tid >> 6, lane = tid & 63;
    const int m = lane & 15, g = lane >> 4;

    if (tid < 128) { isLDS[tid] = invS[tid]; lsLDS[tid] = lS[tid]; }
    stage_centers_T(centers, blds, cnLDS, wid, lane, m, g);  // has __syncthreads

    f32x4 cnr[8], isr[8], lsr[8];
    #pragma unroll
    for (int cb = 0; cb < 8; ++cb) {
        cnr[cb] = *(const f32x4*)&cnLDS[cb * 16 + g * 4];
        isr[cb] = *(const f32x4*)&isLDS[cb * 16 + g * 4];
        lsr[cb] = *(const f32x4*)&lsLDS[cb * 16 + g * 4];
    }

    float loss4[4] = {0.f, 0.f, 0.f, 0.f};
    const int gwid = blockIdx.x * 4 + wid;
    const int nw = nblocks * 4;

    int t = gwid;
    f32x4 n0, n1, n2, n3;
    if (t < NTILES) {
        const float* src = embeds + (size_t)(t * 16 + m) * DIMS + g * 8;
        n0 = *(const f32x4*)src;       n1 = *(const f32x4*)(src + 4);
        n2 = *(const f32x4*)(src + 32); n3 = *(const f32x4*)(src + 36);
    }
    for (; t < NTILES; t += nw) {
        f32x4 c0 = n0, c1 = n1, c2 = n2, c3 = n3;
        int tn = t + nw;
        if (tn < NTILES) {
            const float* src = embeds + (size_t)(tn * 16 + m) * DIMS + g * 8;
            n0 = *(const f32x4*)src;       n1 = *(const f32x4*)(src + 4);
            n2 = *(const f32x4*)(src + 32); n3 = *(const f32x4*)(src + 36);
        }
        bf16x8 a0, a1;
        float en = 0.f;
        #pragma unroll
        for (int j = 0; j < 4; ++j) {
            float f0 = c0[j], f1 = c1[j], f2 = c2[j], f3 = c3[j];
            en += f0 * f0 + f1 * f1 + f2 * f2 + f3 * f3;
            a0[j] = f2bf(f0); a0[j + 4] = f2bf(f1);
            a1[j] = f2bf(f2); a1[j + 4] = f2bf(f3);
        }
        en += __shfl_xor(en, 16);
        en += __shfl_xor(en, 32);

        f32x4 acc[8];
        #pragma unroll
        for (int cb = 0; cb < 8; ++cb) {
            f32x4 a = {en, en, en, en};
            a = __builtin_amdgcn_mfma_f32_16x16x32_bf16(blds[cb][0][lane], a0, a, 0, 0, 0);
            a = __builtin_amdgcn_mfma_f32_16x16x32_bf16(blds[cb][1][lane], a1, a, 0, 0, 0);
            acc[cb] = a;
        }

        // identical split + order as K1 -> bit-identical q
        float rsp4[4] = {0.f, 0.f, 0.f, 0.f};
        #pragma unroll
        for (int cb = 0; cb < 8; ++cb)
            #pragma unroll
            for (int r = 0; r < 4; ++r) {
                float sq = fmaxf(acc[cb][r] + cnr[cb][r], 0.f);
                float dist = frcp(1.0f + sq);
                acc[cb][r] = dist;
                rsp4[r] += dist;
            }
        float rsp = (rsp4[0] + rsp4[1]) + (rsp4[2] + rsp4[3]);
        rsp += __shfl_xor(rsp, 16);
        rsp += __shfl_xor(rsp, 32);
        float invR = frcp(rsp);

        float Wp4[4] = {0.f, 0.f, 0.f, 0.f};
        float* qrow = q + (size_t)(t * 16 + m) * KC + g * 4;
        #pragma unroll
        for (int cb = 0; cb < 8; ++cb)
            #pragma unroll
            for (int r = 0; r < 4; ++r) {
                float qv = acc[cb][r] * invR;
                acc[cb][r] = qv;
                qrow[cb * 16 + r] = qv;
                Wp4[r] += qv * qv * isr[cb][r];
            }
        float Wp = (Wp4[0] + Wp4[1]) + (Wp4[2] + Wp4[3]);
        Wp += __shfl_xor(Wp, 16);
        Wp += __shfl_xor(Wp, 32);
        float iw = frcp(Wp);
        float lw = __log2f(Wp);

        #pragma unroll
        for (int cb = 0; cb < 8; ++cb)
            #pragma unroll
            for (int r = 0; r < 4; ++r) {
                float qv = acc[cb][r];
                float w = qv * qv * isr[cb][r];
                loss4[r] += w * iw * (__log2f(qv) - lsr[cb][r] - lw);
            }
    }

    float loss = (loss4[0] + loss4[1]) + (loss4[2] + loss4[3]);
    loss += __shfl_xor(loss, 1);  loss += __shfl_xor(loss, 2);
    loss += __shfl_xor(loss, 4);  loss += __shfl_xor(loss, 8);
    loss += __shfl_xor(loss, 16); loss += __shfl_xor(loss, 32);
    if (lane == 0) lds4[wid] = loss;
    __syncthreads();
    if (tid == 0) losspart[blockIdx.x] = lds4[0] + lds4[1] + lds4[2] + lds4[3];
}

// K2b: final loss reduce; convert log2 -> ln (R8)
__global__ __launch_bounds__(1024) void k2b_final(
        const float* __restrict__ losspart, int nb, float* __restrict__ out)
{
    __shared__ float lds[16];
    const int tid = threadIdx.x;
    float s = 0.f;
    for (int b = tid; b < nb; b += 1024) s += losspart[b];
    s += __shfl_xor(s, 1);  s += __shfl_xor(s, 2);  s += __shfl_xor(s, 4);
    s += __shfl_xor(s, 8);  s += __shfl_xor(s, 16); s += __shfl_xor(s, 32);
    if ((tid & 63) == 0) lds[tid >> 6] = s;
    __syncthreads();
    if (tid == 0) {
        float tot = 0.f;
        #pragma unroll
        for (int i = 0; i < 16; ++i) tot += lds[i];
        out[0] = (float)((double)tot * 0.6931471805599453 /
                         (double)((size_t)NROWS * KC));
    }
}

extern "C" void kernel_launch(void* const* d_in, const int* in_sizes, int n_in,
                              void* d_out, int out_size, void* d_ws, size_t ws_size,
                              hipStream_t stream)
{
    const float* embeds  = (const float*)d_in[0];
    const float* centers = (const float*)d_in[1];
    float* out  = (float*)d_out;
    float* qbuf = out + 1;
    float* ws   = (float*)d_ws;

    // K1: VGPR ~108 <= 128 -> 4 blocks/CU -> grid 1024.
    // K2: VGPR ~145 >  128 -> 2 blocks/CU -> grid 512 (R8 optimum).
    int GB1 = 1024, GB2 = 512;
    size_t need = ((size_t)GB1 * 128 + 256 + (size_t)GB2) * sizeof(float);
    if (need > ws_size) { GB1 = 512; }

    float* colsum_part = ws;                          // 128 * GB1 (transposed)
    float* invS  = ws + (size_t)GB1 * 128;            // 128
    float* lS    = invS + 128;                        // 128
    float* lpart = lS + 128;                          // GB2

    hipLaunchKernelGGL(k1_colsum, dim3(GB1), dim3(256), 0, stream,
                       embeds, centers, colsum_part, GB1);
    hipLaunchKernelGGL(k1b_reduce, dim3(128), dim3(256), 0, stream,
                       colsum_part, invS, lS, GB1);
    hipLaunchKernelGGL(k2_q_loss, dim3(GB2), dim3(256), 0, stream,
                       embeds, centers, invS, lS, qbuf, lpart, GB2);
    hipLaunchKernelGGL(k2b_final, dim3(1), dim3(1024), 0, stream,
                       lpart, GB2, out);
}

// Round 18
// 100.188 us; speedup vs baseline: 3.1314x; 1.0503x over previous
//
#include <hip/hip_runtime.h>
#include <stdint.h>
#include <stddef.h>

typedef __attribute__((ext_vector_type(8))) short bf16x8;
typedef __attribute__((ext_vector_type(4))) float f32x4;

#define NROWS 400000
#define KC 128
#define DIMS 64
#define NTILES (NROWS / 16)

__device__ __forceinline__ short f2bf(float f) {
    union { float f; uint32_t u; } v; v.f = f;
    uint32_t u = v.u;
    uint32_t r = (u + 0x7FFFu + ((u >> 16) & 1u)) >> 16;  // RNE, finite inputs
    return (short)r;
}

__device__ __forceinline__ float frcp(float x) { return __builtin_amdgcn_rcpf(x); }

// Stage -2*centers bf16 A-fragments into LDS + center norms into cnLDS. (R8 exact)
__device__ __forceinline__ void stage_centers_T(
        const float* __restrict__ centers, bf16x8 (*blds)[2][64],
        float* cnLDS, int wid, int lane, int m, int g)
{
    #pragma unroll
    for (int cb = 0; cb < 8; ++cb) {
        float cacc = 0.f;
        bf16x8 bfr[2];
        #pragma unroll
        for (int h = 0; h < 2; ++h) {
            const float* src = centers + (size_t)(cb * 16 + m) * DIMS + h * 32 + g * 8;
            f32x4 c0 = *(const f32x4*)src;
            f32x4 c1 = *(const f32x4*)(src + 4);
            bf16x8 b;
            #pragma unroll
            for (int j = 0; j < 4; ++j) {
                float f0 = c0[j], f1 = c1[j];
                cacc += f0 * f0 + f1 * f1;
                b[j]     = f2bf(-2.0f * f0);
                b[j + 4] = f2bf(-2.0f * f1);
            }
            bfr[h] = b;
        }
        cacc += __shfl_xor(cacc, 16);
        cacc += __shfl_xor(cacc, 32);
        if (wid == 0) {
            blds[cb][0][lane] = bfr[0];
            blds[cb][1][lane] = bfr[1];
            if (g == 0) cnLDS[cb * 16 + m] = cacc;
        }
    }
    __syncthreads();
}

// K1: column sums of q (R8 exact: cn folded into MFMA C-init, single rsp chain).
__global__ __launch_bounds__(256) void k1_colsum(
        const float* __restrict__ embeds, const float* __restrict__ centers,
        float* __restrict__ colsum_part, int nblocks)
{
    __shared__ bf16x8 blds[8][2][64];
    __shared__ float cnLDS[128];
    __shared__ float cl[4 * 128];
    const int tid = threadIdx.x, wid = tid >> 6, lane = tid & 63;
    const int m = lane & 15, g = lane >> 4;

    stage_centers_T(centers, blds, cnLDS, wid, lane, m, g);

    f32x4 cnr[8];
    #pragma unroll
    for (int cb = 0; cb < 8; ++cb) cnr[cb] = *(const f32x4*)&cnLDS[cb * 16 + g * 4];

    float csum[8][4];
    #pragma unroll
    for (int cb = 0; cb < 8; ++cb)
        #pragma unroll
        for (int r = 0; r < 4; ++r) csum[cb][r] = 0.f;

    const int gwid = blockIdx.x * 4 + wid;
    const int nw = nblocks * 4;

    int t = gwid;
    f32x4 n0, n1, n2, n3;
    if (t < NTILES) {
        const float* src = embeds + (size_t)(t * 16 + m) * DIMS + g * 8;
        n0 = *(const f32x4*)src;       n1 = *(const f32x4*)(src + 4);
        n2 = *(const f32x4*)(src + 32); n3 = *(const f32x4*)(src + 36);
    }
    for (; t < NTILES; t += nw) {
        f32x4 c0 = n0, c1 = n1, c2 = n2, c3 = n3;
        int tn = t + nw;
        if (tn < NTILES) {
            const float* src = embeds + (size_t)(tn * 16 + m) * DIMS + g * 8;
            n0 = *(const f32x4*)src;       n1 = *(const f32x4*)(src + 4);
            n2 = *(const f32x4*)(src + 32); n3 = *(const f32x4*)(src + 36);
        }
        bf16x8 a0, a1;
        float en = 0.f;
        #pragma unroll
        for (int j = 0; j < 4; ++j) {
            float f0 = c0[j], f1 = c1[j], f2 = c2[j], f3 = c3[j];
            en += f0 * f0 + f1 * f1 + f2 * f2 + f3 * f3;
            a0[j] = f2bf(f0); a0[j + 4] = f2bf(f1);
            a1[j] = f2bf(f2); a1[j + 4] = f2bf(f3);
        }
        en += __shfl_xor(en, 16);
        en += __shfl_xor(en, 32);

        f32x4 acc[8];
        #pragma unroll
        for (int cb = 0; cb < 8; ++cb) {
            f32x4 a;
            #pragma unroll
            for (int r = 0; r < 4; ++r) a[r] = cnr[cb][r] + en;   // C = |c|^2 + |e|^2
            a = __builtin_amdgcn_mfma_f32_16x16x32_bf16(blds[cb][0][lane], a0, a, 0, 0, 0);
            a = __builtin_amdgcn_mfma_f32_16x16x32_bf16(blds[cb][1][lane], a1, a, 0, 0, 0);
            acc[cb] = a;
        }

        float rsp = 0.f;
        #pragma unroll
        for (int cb = 0; cb < 8; ++cb)
            #pragma unroll
            for (int r = 0; r < 4; ++r) {
                float dist = frcp(1.0f + fmaxf(acc[cb][r], 0.f));
                acc[cb][r] = dist;
                rsp += dist;
            }
        rsp += __shfl_xor(rsp, 16);
        rsp += __shfl_xor(rsp, 32);
        float invR = frcp(rsp);

        #pragma unroll
        for (int cb = 0; cb < 8; ++cb)
            #pragma unroll
            for (int r = 0; r < 4; ++r) csum[cb][r] += acc[cb][r] * invR;
    }

    #pragma unroll
    for (int cb = 0; cb < 8; ++cb)
        #pragma unroll
        for (int r = 0; r < 4; ++r) {
            float v = csum[cb][r];
            v += __shfl_xor(v, 1); v += __shfl_xor(v, 2);
            v += __shfl_xor(v, 4); v += __shfl_xor(v, 8);
            csum[cb][r] = v;
        }
    if (m == 0) {
        #pragma unroll
        for (int cb = 0; cb < 8; ++cb) {
            f32x4 v = {csum[cb][0], csum[cb][1], csum[cb][2], csum[cb][3]};
            *(f32x4*)&cl[wid * 128 + cb * 16 + g * 4] = v;
        }
    }
    __syncthreads();
    if (tid < 128) {
        float s = cl[tid] + cl[128 + tid] + cl[256 + tid] + cl[384 + tid];
        colsum_part[(size_t)tid * nblocks + blockIdx.x] = s;   // transposed
    }
}

// K1b: 128 blocks, block k reduces contiguous row k -> invS[k] only (lS folded away)
__global__ __launch_bounds__(256) void k1b_reduce(
        const float* __restrict__ part, float* __restrict__ invS, int nb)
{
    __shared__ float lds[4];
    const int k = blockIdx.x;
    const int tid = threadIdx.x, wid = tid >> 6, lane = tid & 63;
    float s = 0.f;
    for (int b = tid; b < nb; b += 256) s += part[(size_t)k * nb + b];
    s += __shfl_xor(s, 1);  s += __shfl_xor(s, 2);  s += __shfl_xor(s, 4);
    s += __shfl_xor(s, 8);  s += __shfl_xor(s, 16); s += __shfl_xor(s, 32);
    if (lane == 0) lds[wid] = s;
    __syncthreads();
    if (tid == 0) invS[k] = 1.0f / (lds[0] + lds[1] + lds[2] + lds[3]);
}

// K2: R8 structure, minus the lsr table: loss term uses log2(qv*isr) - lw
// (log2 q - log2 S == log2(q*invS)). -32 VGPR (136 -> ~104) => 4 blocks/CU.
__global__ __launch_bounds__(256) void k2_q_loss(
        const float* __restrict__ embeds, const float* __restrict__ centers,
        const float* __restrict__ invS,
        float* __restrict__ q, float* __restrict__ losspart, int nblocks)
{
    __shared__ bf16x8 blds[8][2][64];
    __shared__ float cnLDS[128], isLDS[128];
    __shared__ float lds4[4];
    const int tid = threadIdx.x, wid = tid >> 6, lane = tid & 63;
    const int m = lane & 15, g = lane >> 4;

    if (tid < 128) isLDS[tid] = invS[tid];
    stage_centers_T(centers, blds, cnLDS, wid, lane, m, g);  // has __syncthreads

    f32x4 cnr[8], isr[8];
    #pragma unroll
    for (int cb = 0; cb < 8; ++cb) {
        cnr[cb] = *(const f32x4*)&cnLDS[cb * 16 + g * 4];
        isr[cb] = *(const f32x4*)&isLDS[cb * 16 + g * 4];
    }

    float loss = 0.f;
    const int gwid = blockIdx.x * 4 + wid;
    const int nw = nblocks * 4;

    int t = gwid;
    f32x4 n0, n1, n2, n3;
    if (t < NTILES) {
        const float* src = embeds + (size_t)(t * 16 + m) * DIMS + g * 8;
        n0 = *(const f32x4*)src;       n1 = *(const f32x4*)(src + 4);
        n2 = *(const f32x4*)(src + 32); n3 = *(const f32x4*)(src + 36);
    }
    for (; t < NTILES; t += nw) {
        f32x4 c0 = n0, c1 = n1, c2 = n2, c3 = n3;
        int tn = t + nw;
        if (tn < NTILES) {
            const float* src = embeds + (size_t)(tn * 16 + m) * DIMS + g * 8;
            n0 = *(const f32x4*)src;       n1 = *(const f32x4*)(src + 4);
            n2 = *(const f32x4*)(src + 32); n3 = *(const f32x4*)(src + 36);
        }
        bf16x8 a0, a1;
        float en = 0.f;
        #pragma unroll
        for (int j = 0; j < 4; ++j) {
            float f0 = c0[j], f1 = c1[j], f2 = c2[j], f3 = c3[j];
            en += f0 * f0 + f1 * f1 + f2 * f2 + f3 * f3;
            a0[j] = f2bf(f0); a0[j + 4] = f2bf(f1);
            a1[j] = f2bf(f2); a1[j + 4] = f2bf(f3);
        }
        en += __shfl_xor(en, 16);
        en += __shfl_xor(en, 32);

        f32x4 acc[8];
        #pragma unroll
        for (int cb = 0; cb < 8; ++cb) {
            f32x4 a;
            #pragma unroll
            for (int r = 0; r < 4; ++r) a[r] = cnr[cb][r] + en;
            a = __builtin_amdgcn_mfma_f32_16x16x32_bf16(blds[cb][0][lane], a0, a, 0, 0, 0);
            a = __builtin_amdgcn_mfma_f32_16x16x32_bf16(blds[cb][1][lane], a1, a, 0, 0, 0);
            acc[cb] = a;
        }

        float rsp = 0.f;
        #pragma unroll
        for (int cb = 0; cb < 8; ++cb)
            #pragma unroll
            for (int r = 0; r < 4; ++r) {
                float dist = frcp(1.0f + fmaxf(acc[cb][r], 0.f));
                acc[cb][r] = dist;
                rsp += dist;
            }
        rsp += __shfl_xor(rsp, 16);
        rsp += __shfl_xor(rsp, 32);
        float invR = frcp(rsp);

        float Wp = 0.f;
        float* qrow = q + (size_t)(t * 16 + m) * KC + g * 4;
        #pragma unroll
        for (int cb = 0; cb < 8; ++cb)
            #pragma unroll
            for (int r = 0; r < 4; ++r) {
                float qv = acc[cb][r] * invR;
                acc[cb][r] = qv;
                qrow[cb * 16 + r] = qv;
                Wp += qv * qv * isr[cb][r];
            }
        Wp += __shfl_xor(Wp, 16);
        Wp += __shfl_xor(Wp, 32);
        float iw = frcp(Wp);
        float lw = __log2f(Wp);

        #pragma unroll
        for (int cb = 0; cb < 8; ++cb)
            #pragma unroll
            for (int r = 0; r < 4; ++r) {
                float qv = acc[cb][r];
                float w = qv * qv * isr[cb][r];
                loss += w * iw * (__log2f(qv * isr[cb][r]) - lw);
            }
    }

    loss += __shfl_xor(loss, 1);  loss += __shfl_xor(loss, 2);
    loss += __shfl_xor(loss, 4);  loss += __shfl_xor(loss, 8);
    loss += __shfl_xor(loss, 16); loss += __shfl_xor(loss, 32);
    if (lane == 0) lds4[wid] = loss;
    __syncthreads();
    if (tid == 0) losspart[blockIdx.x] = lds4[0] + lds4[1] + lds4[2] + lds4[3];
}

// K2b: final loss reduce; convert log2 -> ln (R8)
__global__ __launch_bounds__(1024) void k2b_final(
        const float* __restrict__ losspart, int nb, float* __restrict__ out)
{
    __shared__ float lds[16];
    const int tid = threadIdx.x;
    float s = 0.f;
    for (int b = tid; b < nb; b += 1024) s += losspart[b];
    s += __shfl_xor(s, 1);  s += __shfl_xor(s, 2);  s += __shfl_xor(s, 4);
    s += __shfl_xor(s, 8);  s += __shfl_xor(s, 16); s += __shfl_xor(s, 32);
    if ((tid & 63) == 0) lds[tid >> 6] = s;
    __syncthreads();
    if (tid == 0) {
        float tot = 0.f;
        #pragma unroll
        for (int i = 0; i < 16; ++i) tot += lds[i];
        out[0] = (float)((double)tot * 0.6931471805599453 /
                         (double)((size_t)NROWS * KC));
    }
}

extern "C" void kernel_launch(void* const* d_in, const int* in_sizes, int n_in,
                              void* d_out, int out_size, void* d_ws, size_t ws_size,
                              hipStream_t stream)
{
    const float* embeds  = (const float*)d_in[0];
    const float* centers = (const float*)d_in[1];
    float* out  = (float*)d_out;
    float* qbuf = out + 1;
    float* ws   = (float*)d_ws;

    // K1: R8 exact (grid 512). K2: lsr-fold drops VGPR ~136->~104 (<=128
    // occupancy granule, m69) -> 4 blocks/CU -> grid 1024.
    int GB1 = 512, GB2 = 1024;
    size_t need = ((size_t)GB1 * 128 + 128 + (size_t)GB2) * sizeof(float);
    if (need > ws_size) { GB2 = 512; }

    float* colsum_part = ws;                          // 128 * GB1 (transposed)
    float* invS  = ws + (size_t)GB1 * 128;            // 128
    float* lpart = invS + 128;                        // GB2

    hipLaunchKernelGGL(k1_colsum, dim3(GB1), dim3(256), 0, stream,
                       embeds, centers, colsum_part, GB1);
    hipLaunchKernelGGL(k1b_reduce, dim3(128), dim3(256), 0, stream,
                       colsum_part, invS, GB1);
    hipLaunchKernelGGL(k2_q_loss, dim3(GB2), dim3(256), 0, stream,
                       embeds, centers, invS, qbuf, lpart, GB2);
    hipLaunchKernelGGL(k2b_final, dim3(1), dim3(1024), 0, stream,
                       lpart, GB2, out);
}